// Round 1
// baseline (930.582 us; speedup 1.0000x reference)
//
#include <hip/hip_runtime.h>
#include <hip/hip_bf16.h>

// Problem constants (validated against in_sizes at launch):
//   N=50000 nodes, E=800000 edges, V=100000 vocab, D=128, G=64, NUM_LAYERS=2
// Inputs: 0 node_ids[N] i32, 1 edge_index[2*E] i32, 2 batch[N] i32 (sorted),
//         3 num_graphs (scalar), 4 embed[V*128] f32, 5 conv_w[2*128*128] f32,
//         6 w_ih[384*128] f32, 7 w_hh[384*128] f32, 8 b_ih[384] f32, 9 b_hh[384] f32
// Output: [64*128] f32 (graph-mean-pooled hidden states)
//
// Workspace layout (~209 MB):
//   h0[N*128], h1[N*128], gi[N*384] (m aliases its first N*128),
//   gh[N*384] (agg aliases its first N*128), cwT[128*128],
//   row_ptr[N+1], counts[N], cursor[N], csr_src[E]
// Aliasing is safe because the stream serializes: m dead before gi GEMM writes,
// agg dead before gh GEMM writes.

#define DTHREADS 256

__device__ __forceinline__ float sigf(float x) { return 1.0f / (1.0f + __expf(-x)); }
__device__ __forceinline__ float tanhfast(float x) { return 1.0f - 2.0f / (1.0f + __expf(2.0f * x)); }

// ---- embed gather: h[n,:] = embed[node_ids[n],:] -------------------------
__global__ __launch_bounds__(DTHREADS) void gather_kernel(
    const float* __restrict__ embed, const int* __restrict__ node_ids,
    float* __restrict__ h, int N) {
  int idx = blockIdx.x * DTHREADS + threadIdx.x;
  if (idx >= N * 32) return;
  int n = idx >> 5;
  int c = (idx & 31) * 4;
  int v = node_ids[n];
  *(float4*)&h[(size_t)n * 128 + c] = *(const float4*)&embed[(size_t)v * 128 + c];
}

// ---- CSR build ------------------------------------------------------------
__global__ __launch_bounds__(DTHREADS) void hist_kernel(
    const int* __restrict__ dst, int* __restrict__ counts, int E) {
  int e = blockIdx.x * DTHREADS + threadIdx.x;
  if (e < E) atomicAdd(&counts[dst[e]], 1);
}

// single-block exclusive scan (wave shuffles, few barriers per 1024-chunk)
__global__ __launch_bounds__(1024) void scan_kernel(
    const int* __restrict__ counts, int* __restrict__ row_ptr,
    int* __restrict__ cursor, int N) {
  __shared__ int wsum[16];
  __shared__ int carry_s;
  const int tid = threadIdx.x;
  const int lane = tid & 63;
  const int wv = tid >> 6;
  if (tid == 0) carry_s = 0;
  __syncthreads();
  for (int base = 0; base < N; base += 1024) {
    int i = base + tid;
    int v = (i < N) ? counts[i] : 0;
    int x = v;
    #pragma unroll
    for (int off = 1; off < 64; off <<= 1) {
      int y = __shfl_up(x, (unsigned)off, 64);
      if (lane >= off) x += y;
    }
    if (lane == 63) wsum[wv] = x;
    __syncthreads();
    if (wv == 0) {
      int s = (lane < 16) ? wsum[lane] : 0;
      #pragma unroll
      for (int off = 1; off < 16; off <<= 1) {
        int y = __shfl_up(s, (unsigned)off, 64);
        if (lane >= off) s += y;
      }
      if (lane < 16) wsum[lane] = s;
    }
    __syncthreads();
    int waveoff = (wv == 0) ? 0 : wsum[wv - 1];
    int excl = carry_s + waveoff + (x - v);
    if (i < N) { row_ptr[i] = excl; cursor[i] = excl; }
    __syncthreads();
    if (tid == 0) carry_s += wsum[15];
    __syncthreads();
  }
  if (tid == 0) row_ptr[N] = carry_s;
}

__global__ __launch_bounds__(DTHREADS) void fill_kernel(
    const int* __restrict__ src, const int* __restrict__ dst,
    int* __restrict__ cursor, int* __restrict__ csr_src, int E) {
  int e = blockIdx.x * DTHREADS + threadIdx.x;
  if (e >= E) return;
  int slot = atomicAdd(&cursor[dst[e]], 1);
  csr_src[slot] = src[e];
}

// ---- conv_w transpose: cwT[j][k] = cw[k][j] ------------------------------
__global__ __launch_bounds__(DTHREADS) void transpose_kernel(
    const float* __restrict__ cw, float* __restrict__ cwT) {
  int idx = blockIdx.x * DTHREADS + threadIdx.x;
  if (idx >= 128 * 128) return;
  int j = idx >> 7, k = idx & 127;
  cwT[idx] = cw[k * 128 + j];
}

// ---- fp32 tiled GEMM: C[N x J] = A[N x 128] * Bt[J x 128]^T + bias[J] ----
// 64x64 tile / block of 256 threads / 4x4 register tile per thread.
__global__ __launch_bounds__(DTHREADS) void gemm_nt(
    const float* __restrict__ A, const float* __restrict__ Bt,
    const float* __restrict__ bias, float* __restrict__ C, int N, int J) {
  __shared__ float As[32][68];  // [k][n], padded row stride 68 (272B, 16B-aligned)
  __shared__ float Bs[32][68];  // [k][j]
  const int tid = threadIdx.x;
  const int n_base = blockIdx.x * 64;
  const int j_base = blockIdx.y * 64;
  const int r0 = tid >> 3;        // 0..31 (row within half-tile)
  const int k4 = (tid & 7) * 4;   // 0..28
  const int an0 = (tid >> 4) * 4; // 0..60
  const int bj0 = (tid & 15) * 4; // 0..60
  float acc[4][4] = {{0.f}};

  for (int kc = 0; kc < 128; kc += 32) {
    #pragma unroll
    for (int half = 0; half < 2; ++half) {
      int nl = r0 + half * 32;
      int n = n_base + nl;
      float4 av = make_float4(0.f, 0.f, 0.f, 0.f);
      if (n < N) av = *(const float4*)&A[(size_t)n * 128 + kc + k4];
      As[k4 + 0][nl] = av.x; As[k4 + 1][nl] = av.y;
      As[k4 + 2][nl] = av.z; As[k4 + 3][nl] = av.w;
      int j = j_base + nl;  // J is a multiple of 64 -> always in range
      float4 bv = *(const float4*)&Bt[(size_t)j * 128 + kc + k4];
      Bs[k4 + 0][nl] = bv.x; Bs[k4 + 1][nl] = bv.y;
      Bs[k4 + 2][nl] = bv.z; Bs[k4 + 3][nl] = bv.w;
    }
    __syncthreads();
    #pragma unroll
    for (int k = 0; k < 32; ++k) {
      float4 a = *(const float4*)&As[k][an0];
      float4 b = *(const float4*)&Bs[k][bj0];
      acc[0][0] += a.x * b.x; acc[0][1] += a.x * b.y; acc[0][2] += a.x * b.z; acc[0][3] += a.x * b.w;
      acc[1][0] += a.y * b.x; acc[1][1] += a.y * b.y; acc[1][2] += a.y * b.z; acc[1][3] += a.y * b.w;
      acc[2][0] += a.z * b.x; acc[2][1] += a.z * b.y; acc[2][2] += a.z * b.z; acc[2][3] += a.z * b.w;
      acc[3][0] += a.w * b.x; acc[3][1] += a.w * b.y; acc[3][2] += a.w * b.z; acc[3][3] += a.w * b.w;
    }
    __syncthreads();
  }

  float4 bvec = make_float4(0.f, 0.f, 0.f, 0.f);
  if (bias) bvec = *(const float4*)&bias[j_base + bj0];
  #pragma unroll
  for (int i = 0; i < 4; ++i) {
    int n = n_base + an0 + i;
    if (n < N) {
      float4 o;
      o.x = acc[i][0] + bvec.x; o.y = acc[i][1] + bvec.y;
      o.z = acc[i][2] + bvec.z; o.w = acc[i][3] + bvec.w;
      *(float4*)&C[(size_t)n * J + j_base + bj0] = o;
    }
  }
}

// ---- CSR aggregate: agg[n,:] = sum_{e: dst==n} m[src[e],:] ---------------
// one wave per node; lane holds float2 (64*8B = 512B row)
__global__ __launch_bounds__(DTHREADS) void aggregate_kernel(
    const float* __restrict__ m, const int* __restrict__ row_ptr,
    const int* __restrict__ csr_src, float* __restrict__ agg, int N) {
  int w = (blockIdx.x * DTHREADS + threadIdx.x) >> 6;
  int lane = threadIdx.x & 63;
  if (w >= N) return;
  int s = row_ptr[w], e = row_ptr[w + 1];
  float2 acc = make_float2(0.f, 0.f);
  for (int i = s; i < e; ++i) {
    int src = csr_src[i];
    float2 v = *(const float2*)&m[(size_t)src * 128 + lane * 2];
    acc.x += v.x; acc.y += v.y;
  }
  *(float2*)&agg[(size_t)w * 128 + lane * 2] = acc;
}

// ---- GRU gates: h_out = (1-z)*tanh(i_n + r*h_n) + z*h --------------------
__global__ __launch_bounds__(DTHREADS) void gates_kernel(
    const float* __restrict__ gi, const float* __restrict__ gh,
    const float* __restrict__ h, float* __restrict__ h_out, int N) {
  int idx = blockIdx.x * DTHREADS + threadIdx.x;
  if (idx >= N * 32) return;
  int n = idx >> 5;
  int j = (idx & 31) * 4;
  size_t gbase = (size_t)n * 384 + j;
  float4 ir = *(const float4*)&gi[gbase];
  float4 iz = *(const float4*)&gi[gbase + 128];
  float4 in_ = *(const float4*)&gi[gbase + 256];
  float4 hr = *(const float4*)&gh[gbase];
  float4 hz = *(const float4*)&gh[gbase + 128];
  float4 hn = *(const float4*)&gh[gbase + 256];
  float4 hv = *(const float4*)&h[(size_t)n * 128 + j];
  float4 o;
  {
    float r = sigf(ir.x + hr.x), z = sigf(iz.x + hz.x);
    float ng = tanhfast(in_.x + r * hn.x);
    o.x = (1.f - z) * ng + z * hv.x;
  }
  {
    float r = sigf(ir.y + hr.y), z = sigf(iz.y + hz.y);
    float ng = tanhfast(in_.y + r * hn.y);
    o.y = (1.f - z) * ng + z * hv.y;
  }
  {
    float r = sigf(ir.z + hr.z), z = sigf(iz.z + hz.z);
    float ng = tanhfast(in_.z + r * hn.z);
    o.z = (1.f - z) * ng + z * hv.z;
  }
  {
    float r = sigf(ir.w + hr.w), z = sigf(iz.w + hz.w);
    float ng = tanhfast(in_.w + r * hn.w);
    o.w = (1.f - z) * ng + z * hv.w;
  }
  *(float4*)&h_out[(size_t)n * 128 + j] = o;
}

// ---- per-graph mean pool (batch sorted; binary-search the range) ---------
__device__ __forceinline__ int lbound(const int* a, int n, int key) {
  int lo = 0, hi = n;
  while (lo < hi) {
    int mid = (lo + hi) >> 1;
    if (a[mid] < key) lo = mid + 1; else hi = mid;
  }
  return lo;
}

__global__ __launch_bounds__(DTHREADS) void pool_kernel(
    const float* __restrict__ h, const int* __restrict__ batch,
    float* __restrict__ out, int N) {
  int g = blockIdx.x;
  int lo = lbound(batch, N, g);
  int hi = lbound(batch, N, g + 1);
  int c = threadIdx.x & 127;
  int half = threadIdx.x >> 7;
  float acc = 0.f;
  for (int i = lo + half; i < hi; i += 2) acc += h[(size_t)i * 128 + c];
  __shared__ float red[256];
  red[threadIdx.x] = acc;
  __syncthreads();
  if (half == 0) {
    float s = red[c] + red[c + 128];
    int cnt = hi - lo;
    out[(size_t)g * 128 + c] = s / (float)max(cnt, 1);
  }
}

extern "C" void kernel_launch(void* const* d_in, const int* in_sizes, int n_in,
                              void* d_out, int out_size, void* d_ws, size_t ws_size,
                              hipStream_t stream) {
  const int* node_ids = (const int*)d_in[0];
  const int* edge_index = (const int*)d_in[1];
  const int* batch = (const int*)d_in[2];
  const float* embed = (const float*)d_in[4];
  const float* conv_w = (const float*)d_in[5];
  const float* w_ih = (const float*)d_in[6];
  const float* w_hh = (const float*)d_in[7];
  const float* b_ih = (const float*)d_in[8];
  const float* b_hh = (const float*)d_in[9];
  float* out = (float*)d_out;

  const int N = in_sizes[0];
  const int E = in_sizes[1] / 2;
  const int G = out_size / 128;
  const int NUM_LAYERS = in_sizes[5] / (128 * 128);

  const int* e_src = edge_index;       // row 0
  const int* e_dst = edge_index + E;   // row 1

  // workspace carve-up
  float* h0 = (float*)d_ws;
  float* h1 = h0 + (size_t)N * 128;
  float* gi = h1 + (size_t)N * 128;    // m aliases gi[0 : N*128]
  float* gh = gi + (size_t)N * 384;    // agg aliases gh[0 : N*128]
  float* cwT = gh + (size_t)N * 384;
  int* row_ptr = (int*)(cwT + 128 * 128);
  int* counts = row_ptr + (N + 1);
  int* cursor = counts + N;
  int* csr_src = cursor + N;
  float* m = gi;
  float* agg = gh;

  const int nb = (N + 63) / 64;

  // CSR build (once; reused by both layers)
  hipMemsetAsync(counts, 0, (size_t)N * sizeof(int), stream);
  hist_kernel<<<(E + DTHREADS - 1) / DTHREADS, DTHREADS, 0, stream>>>(e_dst, counts, E);
  scan_kernel<<<1, 1024, 0, stream>>>(counts, row_ptr, cursor, N);
  fill_kernel<<<(E + DTHREADS - 1) / DTHREADS, DTHREADS, 0, stream>>>(e_src, e_dst, cursor, csr_src, E);

  // h = embed[node_ids]
  gather_kernel<<<(N * 32 + DTHREADS - 1) / DTHREADS, DTHREADS, 0, stream>>>(embed, node_ids, h0, N);

  for (int L = 0; L < NUM_LAYERS; ++L) {
    const float* hin = (L % 2 == 0) ? h0 : h1;
    float* hout = (L % 2 == 0) ? h1 : h0;
    transpose_kernel<<<64, DTHREADS, 0, stream>>>(conv_w + (size_t)L * 128 * 128, cwT);
    // m = hin @ conv_w[L]
    gemm_nt<<<dim3(nb, 2), DTHREADS, 0, stream>>>(hin, cwT, nullptr, m, N, 128);
    // agg = segment_sum(m[src], dst)
    aggregate_kernel<<<((size_t)N * 64 + DTHREADS - 1) / DTHREADS, DTHREADS, 0, stream>>>(
        m, row_ptr, csr_src, agg, N);
    // gi = agg @ w_ih^T + b_ih ; gh = hin @ w_hh^T + b_hh
    gemm_nt<<<dim3(nb, 6), DTHREADS, 0, stream>>>(agg, w_ih, b_ih, gi, N, 384);
    gemm_nt<<<dim3(nb, 6), DTHREADS, 0, stream>>>(hin, w_hh, b_hh, gh, N, 384);
    gates_kernel<<<(N * 32 + DTHREADS - 1) / DTHREADS, DTHREADS, 0, stream>>>(gi, gh, hin, hout, N);
  }

  const float* hfin = (NUM_LAYERS % 2 == 0) ? h0 : h1;
  pool_kernel<<<G, DTHREADS, 0, stream>>>(hfin, batch, out, N);
}

// Round 2
// 648.542 us; speedup vs baseline: 1.4349x; 1.4349x over previous
//
#include <hip/hip_runtime.h>
#include <hip/hip_bf16.h>

// GatedConv: N=50000 nodes, E=800000 edges, D=128, G=64, 2 layers.
// Round 1: bf16 MFMA GEMMs (16x16x32), fragment-prepacked weights,
// two-stage mean pool. Intermediates gi/gh stay fp32 for accuracy.

#define DTHREADS 256

typedef __attribute__((ext_vector_type(8))) short bf16x8;
typedef __attribute__((ext_vector_type(4))) float f32x4;

__device__ __forceinline__ float sigf(float x) { return 1.0f / (1.0f + __expf(-x)); }
__device__ __forceinline__ float tanhfast(float x) { return 1.0f - 2.0f / (1.0f + __expf(2.0f * x)); }

__device__ __forceinline__ unsigned short f2bf_rne(float x) {
  unsigned int u = __float_as_uint(x);
  u += 0x7fff + ((u >> 16) & 1);
  return (unsigned short)(u >> 16);
}
__device__ __forceinline__ float bf2f(unsigned int lo16) {
  return __uint_as_float(lo16 << 16);
}

// ---- embed gather: h fp32 + hb bf16 --------------------------------------
__global__ __launch_bounds__(DTHREADS) void gather_kernel(
    const float* __restrict__ embed, const int* __restrict__ node_ids,
    float* __restrict__ h, unsigned short* __restrict__ hb, int N) {
  int idx = blockIdx.x * DTHREADS + threadIdx.x;
  if (idx >= N * 32) return;
  int n = idx >> 5;
  int c = (idx & 31) * 4;
  int v = node_ids[n];
  float4 val = *(const float4*)&embed[(size_t)v * 128 + c];
  *(float4*)&h[(size_t)n * 128 + c] = val;
  unsigned short b[4] = {f2bf_rne(val.x), f2bf_rne(val.y), f2bf_rne(val.z), f2bf_rne(val.w)};
  *(ushort4*)&hb[(size_t)n * 128 + c] = *(ushort4*)b;
}

// ---- CSR build ------------------------------------------------------------
__global__ __launch_bounds__(DTHREADS) void hist_kernel(
    const int* __restrict__ dst, int* __restrict__ counts, int E) {
  int e = blockIdx.x * DTHREADS + threadIdx.x;
  if (e < E) atomicAdd(&counts[dst[e]], 1);
}

__global__ __launch_bounds__(1024) void scan_kernel(
    const int* __restrict__ counts, int* __restrict__ row_ptr,
    int* __restrict__ cursor, int N) {
  __shared__ int wsum[16];
  __shared__ int carry_s;
  const int tid = threadIdx.x;
  const int lane = tid & 63;
  const int wv = tid >> 6;
  if (tid == 0) carry_s = 0;
  __syncthreads();
  for (int base = 0; base < N; base += 1024) {
    int i = base + tid;
    int v = (i < N) ? counts[i] : 0;
    int x = v;
    #pragma unroll
    for (int off = 1; off < 64; off <<= 1) {
      int y = __shfl_up(x, (unsigned)off, 64);
      if (lane >= off) x += y;
    }
    if (lane == 63) wsum[wv] = x;
    __syncthreads();
    if (wv == 0) {
      int s = (lane < 16) ? wsum[lane] : 0;
      #pragma unroll
      for (int off = 1; off < 16; off <<= 1) {
        int y = __shfl_up(s, (unsigned)off, 64);
        if (lane >= off) s += y;
      }
      if (lane < 16) wsum[lane] = s;
    }
    __syncthreads();
    int waveoff = (wv == 0) ? 0 : wsum[wv - 1];
    int excl = carry_s + waveoff + (x - v);
    if (i < N) { row_ptr[i] = excl; cursor[i] = excl; }
    __syncthreads();
    if (tid == 0) carry_s += wsum[15];
    __syncthreads();
  }
  if (tid == 0) row_ptr[N] = carry_s;
}

__global__ __launch_bounds__(DTHREADS) void fill_kernel(
    const int* __restrict__ src, const int* __restrict__ dst,
    int* __restrict__ cursor, int* __restrict__ csr_src, int E) {
  int e = blockIdx.x * DTHREADS + threadIdx.x;
  if (e >= E) return;
  int slot = atomicAdd(&cursor[dst[e]], 1);
  csr_src[slot] = src[e];
}

// ---- weight pack: fp32 -> bf16 in MFMA B-fragment order ------------------
// wpk flat index f = ((jb*4 + t)*4 + s)*64 + l ; holds 8 bf16:
//   j = jb*64 + t*16 + (l&15), k = s*32 + (l>>4)*8 + i
// trans=0: src w[j*128+k] (w_ih/w_hh are [J][K]); trans=1: src w[k*128+j] (conv_w is [K][J])
__global__ __launch_bounds__(DTHREADS) void pack_w_kernel(
    const float* __restrict__ w, unsigned short* __restrict__ wpk, int J, int trans) {
  int f = blockIdx.x * DTHREADS + threadIdx.x;
  if (f >= J * 16) return;
  int l = f & 63;
  int s = (f >> 6) & 3;
  int t = (f >> 8) & 3;
  int jb = f >> 10;
  int j = jb * 64 + t * 16 + (l & 15);
  int kb = s * 32 + (l >> 4) * 8;
  unsigned short o[8];
  #pragma unroll
  for (int i = 0; i < 8; ++i) {
    int k = kb + i;
    float v = trans ? w[k * 128 + j] : w[j * 128 + k];
    o[i] = f2bf_rne(v);
  }
  *(uint4*)&wpk[(size_t)f * 8] = *(uint4*)o;
}

// ---- bf16 MFMA GEMM: C[N x J] = A[N x 128] @ W^T + bias ------------------
// BM=128, BN=64, full K=128 in LDS (XOR-swizzled 16B chunks). 4 waves:
// wave w computes rows [w*32, w*32+32), all 64 j of this j-block.
template <int OUT_BF16>
__global__ __launch_bounds__(DTHREADS) void mfma_gemm(
    const unsigned short* __restrict__ A, const unsigned short* __restrict__ Wpk,
    const float* __restrict__ bias, void* __restrict__ C, int N, int J) {
  __shared__ __align__(16) unsigned short As[128 * 128];  // 32 KB
  const int tid = threadIdx.x;
  const int n0 = blockIdx.x * 128;
  const int jb = blockIdx.y;

  // stage A tile (rows n0..n0+127, all K) with 16B-chunk xor swizzle
  #pragma unroll
  for (int it = 0; it < 8; ++it) {
    int c = it * 256 + tid;        // 0..2047
    int row = c >> 4, col = c & 15;
    int n = n0 + row;
    uint4 v = make_uint4(0, 0, 0, 0);
    if (n < N) v = *(const uint4*)&A[(size_t)n * 128 + col * 8];
    int dc = col ^ (row & 15);
    *(uint4*)&As[row * 128 + dc * 8] = v;
  }
  __syncthreads();

  const int wv = tid >> 6, lane = tid & 63;
  const int lm = lane & 15, quad = lane >> 4;

  f32x4 acc[2][4];
  #pragma unroll
  for (int a = 0; a < 2; ++a)
    #pragma unroll
    for (int b = 0; b < 4; ++b) acc[a][b] = (f32x4){0.f, 0.f, 0.f, 0.f};

  const unsigned short* wbase = Wpk + (size_t)jb * 1024 * 8;  // 16 groups * 64 lanes * 8

  #pragma unroll
  for (int s = 0; s < 4; ++s) {
    bf16x8 afr[2];
    #pragma unroll
    for (int mi = 0; mi < 2; ++mi) {
      int m = wv * 32 + mi * 16 + lm;
      int chunk = (s * 4 + quad) ^ (m & 15);
      afr[mi] = *(const bf16x8*)&As[m * 128 + chunk * 8];
    }
    #pragma unroll
    for (int t = 0; t < 4; ++t) {
      bf16x8 bfr = *(const bf16x8*)&wbase[((size_t)(t * 4 + s) * 64 + lane) * 8];
      acc[0][t] = __builtin_amdgcn_mfma_f32_16x16x32_bf16(afr[0], bfr, acc[0][t], 0, 0, 0);
      acc[1][t] = __builtin_amdgcn_mfma_f32_16x16x32_bf16(afr[1], bfr, acc[1][t], 0, 0, 0);
    }
  }

  // C/D layout: col = lane&15, row = quad*4 + reg
  #pragma unroll
  for (int mi = 0; mi < 2; ++mi) {
    int nbase = n0 + wv * 32 + mi * 16 + quad * 4;
    #pragma unroll
    for (int t = 0; t < 4; ++t) {
      int j = jb * 64 + t * 16 + lm;
      float bv = bias ? bias[j] : 0.f;
      #pragma unroll
      for (int r = 0; r < 4; ++r) {
        int n = nbase + r;
        if (n < N) {
          float o = acc[mi][t][r] + bv;
          if (OUT_BF16)
            ((unsigned short*)C)[(size_t)n * J + j] = f2bf_rne(o);
          else
            ((float*)C)[(size_t)n * J + j] = o;
        }
      }
    }
  }
}

// ---- CSR aggregate over bf16 m, fp32 accum, bf16 out ---------------------
__global__ __launch_bounds__(DTHREADS) void aggregate_kernel(
    const unsigned short* __restrict__ m, const int* __restrict__ row_ptr,
    const int* __restrict__ csr_src, unsigned short* __restrict__ agg, int N) {
  int w = (blockIdx.x * DTHREADS + threadIdx.x) >> 6;
  int lane = threadIdx.x & 63;
  if (w >= N) return;
  int s = row_ptr[w], e = row_ptr[w + 1];
  float ax = 0.f, ay = 0.f;
  for (int i = s; i < e; ++i) {
    int src = csr_src[i];
    unsigned int v = *(const unsigned int*)&m[(size_t)src * 128 + lane * 2];
    ax += bf2f(v & 0xffffu);
    ay += bf2f(v >> 16);
  }
  unsigned int o = (unsigned int)f2bf_rne(ax) | ((unsigned int)f2bf_rne(ay) << 16);
  *(unsigned int*)&agg[(size_t)w * 128 + lane * 2] = o;
}

// ---- GRU gates (in-place h update) + bf16 h ------------------------------
__global__ __launch_bounds__(DTHREADS) void gates_kernel(
    const float* __restrict__ gi, const float* __restrict__ gh,
    float* __restrict__ h, unsigned short* __restrict__ hb, int N) {
  int idx = blockIdx.x * DTHREADS + threadIdx.x;
  if (idx >= N * 32) return;
  int n = idx >> 5;
  int j = (idx & 31) * 4;
  size_t gbase = (size_t)n * 384 + j;
  float4 ir = *(const float4*)&gi[gbase];
  float4 iz = *(const float4*)&gi[gbase + 128];
  float4 in_ = *(const float4*)&gi[gbase + 256];
  float4 hr = *(const float4*)&gh[gbase];
  float4 hz = *(const float4*)&gh[gbase + 128];
  float4 hn = *(const float4*)&gh[gbase + 256];
  float4 hv = *(const float4*)&h[(size_t)n * 128 + j];
  float4 o;
  {
    float r = sigf(ir.x + hr.x), z = sigf(iz.x + hz.x);
    o.x = (1.f - z) * tanhfast(in_.x + r * hn.x) + z * hv.x;
  }
  {
    float r = sigf(ir.y + hr.y), z = sigf(iz.y + hz.y);
    o.y = (1.f - z) * tanhfast(in_.y + r * hn.y) + z * hv.y;
  }
  {
    float r = sigf(ir.z + hr.z), z = sigf(iz.z + hz.z);
    o.z = (1.f - z) * tanhfast(in_.z + r * hn.z) + z * hv.z;
  }
  {
    float r = sigf(ir.w + hr.w), z = sigf(iz.w + hz.w);
    o.w = (1.f - z) * tanhfast(in_.w + r * hn.w) + z * hv.w;
  }
  *(float4*)&h[(size_t)n * 128 + j] = o;
  unsigned short b[4] = {f2bf_rne(o.x), f2bf_rne(o.y), f2bf_rne(o.z), f2bf_rne(o.w)};
  *(ushort4*)&hb[(size_t)n * 128 + j] = *(ushort4*)b;
}

// ---- two-stage mean pool -------------------------------------------------
__global__ __launch_bounds__(DTHREADS) void pool1_kernel(
    const float* __restrict__ h, const int* __restrict__ batch,
    float* __restrict__ outsum, int N) {
  int b = blockIdx.x;
  int c = threadIdx.x & 127;
  int half = threadIdx.x >> 7;
  int nbeg = b * 64;
  int nend = min(nbeg + 64, N);
  float acc = 0.f;
  int cur = -1;
  for (int n = nbeg + half; n < nend; n += 2) {
    int g = batch[n];
    if (g != cur) {
      if (cur >= 0) atomicAdd(&outsum[(size_t)cur * 128 + c], acc);
      acc = 0.f;
      cur = g;
    }
    acc += h[(size_t)n * 128 + c];
  }
  if (cur >= 0) atomicAdd(&outsum[(size_t)cur * 128 + c], acc);
}

__device__ __forceinline__ int lbound(const int* a, int n, int key) {
  int lo = 0, hi = n;
  while (lo < hi) {
    int mid = (lo + hi) >> 1;
    if (a[mid] < key) lo = mid + 1; else hi = mid;
  }
  return lo;
}

__global__ __launch_bounds__(128) void pool2_kernel(
    const float* __restrict__ outsum, const int* __restrict__ batch,
    float* __restrict__ out, int N) {
  int g = blockIdx.x;
  int c = threadIdx.x;
  int lo = lbound(batch, N, g);
  int hi = lbound(batch, N, g + 1);
  out[(size_t)g * 128 + c] = outsum[(size_t)g * 128 + c] / (float)max(hi - lo, 1);
}

extern "C" void kernel_launch(void* const* d_in, const int* in_sizes, int n_in,
                              void* d_out, int out_size, void* d_ws, size_t ws_size,
                              hipStream_t stream) {
  const int* node_ids = (const int*)d_in[0];
  const int* edge_index = (const int*)d_in[1];
  const int* batch = (const int*)d_in[2];
  const float* embed = (const float*)d_in[4];
  const float* conv_w = (const float*)d_in[5];
  const float* w_ih = (const float*)d_in[6];
  const float* w_hh = (const float*)d_in[7];
  const float* b_ih = (const float*)d_in[8];
  const float* b_hh = (const float*)d_in[9];
  float* out = (float*)d_out;

  const int N = in_sizes[0];
  const int E = in_sizes[1] / 2;
  const int G = out_size / 128;
  const int NUM_LAYERS = in_sizes[5] / (128 * 128);

  const int* e_src = edge_index;
  const int* e_dst = edge_index + E;

  // ---- workspace carve-up (all 16B aligned) ----
  char* p = (char*)d_ws;
  float* h = (float*)p;                 p += (size_t)N * 128 * 4;
  float* gi = (float*)p;                p += (size_t)N * 384 * 4;
  float* gh = (float*)p;                p += (size_t)N * 384 * 4;
  unsigned short* hb = (unsigned short*)p;  p += (size_t)N * 128 * 2;
  float* outsum = (float*)p;            p += (size_t)G * 128 * 4;
  unsigned short* wpk_conv = (unsigned short*)p;  p += (size_t)NUM_LAYERS * 128 * 128 * 2;
  unsigned short* wpk_ih = (unsigned short*)p;    p += (size_t)384 * 128 * 2;
  unsigned short* wpk_hh = (unsigned short*)p;    p += (size_t)384 * 128 * 2;
  int* row_ptr = (int*)p;               p += (size_t)(N + 1) * 4;
  int* counts = (int*)p;                p += (size_t)N * 4;
  int* cursor = (int*)p;                p += (size_t)N * 4;
  int* csr_src = (int*)p;               p += (size_t)E * 4;
  // aliases (lifetimes disjoint; stream serializes):
  unsigned short* mb = (unsigned short*)gi;   // m bf16, dead before gi GEMM writes
  unsigned short* aggb = (unsigned short*)gh; // agg bf16, dead before gh GEMM writes

  // CSR build (reused by both layers)
  hipMemsetAsync(counts, 0, (size_t)N * sizeof(int), stream);
  hipMemsetAsync(outsum, 0, (size_t)G * 128 * sizeof(float), stream);
  hist_kernel<<<(E + DTHREADS - 1) / DTHREADS, DTHREADS, 0, stream>>>(e_dst, counts, E);
  scan_kernel<<<1, 1024, 0, stream>>>(counts, row_ptr, cursor, N);
  fill_kernel<<<(E + DTHREADS - 1) / DTHREADS, DTHREADS, 0, stream>>>(e_src, e_dst, cursor, csr_src, E);

  // weight packing (bf16, fragment order)
  for (int L = 0; L < NUM_LAYERS; ++L)
    pack_w_kernel<<<(128 * 16 + DTHREADS - 1) / DTHREADS, DTHREADS, 0, stream>>>(
        conv_w + (size_t)L * 128 * 128, wpk_conv + (size_t)L * 128 * 128, 128, 1);
  pack_w_kernel<<<(384 * 16 + DTHREADS - 1) / DTHREADS, DTHREADS, 0, stream>>>(w_ih, wpk_ih, 384, 0);
  pack_w_kernel<<<(384 * 16 + DTHREADS - 1) / DTHREADS, DTHREADS, 0, stream>>>(w_hh, wpk_hh, 384, 0);

  // h = embed[node_ids] (fp32 + bf16)
  gather_kernel<<<(N * 32 + DTHREADS - 1) / DTHREADS, DTHREADS, 0, stream>>>(embed, node_ids, h, hb, N);

  const int nb = (N + 127) / 128;
  for (int L = 0; L < NUM_LAYERS; ++L) {
    // m = h @ conv_w[L]  (bf16 out)
    mfma_gemm<1><<<dim3(nb, 2), DTHREADS, 0, stream>>>(
        hb, wpk_conv + (size_t)L * 128 * 128, nullptr, mb, N, 128);
    // agg = segment_sum(m[src], dst)  (bf16 out)
    aggregate_kernel<<<((size_t)N * 64 + DTHREADS - 1) / DTHREADS, DTHREADS, 0, stream>>>(
        mb, row_ptr, csr_src, aggb, N);
    // gi = agg @ w_ih^T + b_ih ; gh = h @ w_hh^T + b_hh  (fp32 out)
    mfma_gemm<0><<<dim3(nb, 6), DTHREADS, 0, stream>>>(aggb, wpk_ih, b_ih, gi, N, 384);
    mfma_gemm<0><<<dim3(nb, 6), DTHREADS, 0, stream>>>(hb, wpk_hh, b_hh, gh, N, 384);
    // h = GRU(agg, h) in place; refresh hb
    gates_kernel<<<(N * 32 + DTHREADS - 1) / DTHREADS, DTHREADS, 0, stream>>>(gi, gh, h, hb, N);
  }

  pool1_kernel<<<(N + 63) / 64, DTHREADS, 0, stream>>>(h, batch, outsum, N);
  pool2_kernel<<<G, 128, 0, stream>>>(outsum, batch, out, N);
}

// Round 3
// 576.769 us; speedup vs baseline: 1.6134x; 1.1244x over previous
//
#include <hip/hip_runtime.h>
#include <hip/hip_bf16.h>

// GatedConv: N=50000, E=800000, D=128, G=64, 2 layers.
// Round 2: (a) conv GEMM folded into gi GEMM via Wc = conv_w @ w_ih^T
// (segment_sum is linear, so segsum(h@W)[dst] = segsum(h)[dst] @ W);
// (b) aggregate processes 4 edges/iteration with uint4 loads + shfl reduce;
// (c) all intermediates bf16 (gi/gh/h-state), fp32 accumulation everywhere.

#define DTHREADS 256

typedef __attribute__((ext_vector_type(8))) short bf16x8;
typedef __attribute__((ext_vector_type(4))) float f32x4;

__device__ __forceinline__ float sigf(float x) { return 1.0f / (1.0f + __expf(-x)); }
__device__ __forceinline__ float tanhfast(float x) { return 1.0f - 2.0f / (1.0f + __expf(2.0f * x)); }

__device__ __forceinline__ unsigned short f2bf_rne(float x) {
  unsigned int u = __float_as_uint(x);
  u += 0x7fff + ((u >> 16) & 1);
  return (unsigned short)(u >> 16);
}
__device__ __forceinline__ float bf2f(unsigned int lo16) {
  return __uint_as_float(lo16 << 16);
}

// ---- embed gather: hb[n,:] = bf16(embed[node_ids[n],:]) ------------------
__global__ __launch_bounds__(DTHREADS) void gather_kernel(
    const float* __restrict__ embed, const int* __restrict__ node_ids,
    unsigned short* __restrict__ hb, int N) {
  int idx = blockIdx.x * DTHREADS + threadIdx.x;
  if (idx >= N * 32) return;
  int n = idx >> 5;
  int c = (idx & 31) * 4;
  int v = node_ids[n];
  float4 val = *(const float4*)&embed[(size_t)v * 128 + c];
  unsigned short b[4] = {f2bf_rne(val.x), f2bf_rne(val.y), f2bf_rne(val.z), f2bf_rne(val.w)};
  *(ushort4*)&hb[(size_t)n * 128 + c] = *(ushort4*)b;
}

// ---- CSR build ------------------------------------------------------------
__global__ __launch_bounds__(DTHREADS) void hist_kernel(
    const int* __restrict__ dst, int* __restrict__ counts, int E) {
  int e = blockIdx.x * DTHREADS + threadIdx.x;
  if (e < E) atomicAdd(&counts[dst[e]], 1);
}

__global__ __launch_bounds__(1024) void scan_kernel(
    const int* __restrict__ counts, int* __restrict__ row_ptr,
    int* __restrict__ cursor, int N) {
  __shared__ int wsum[16];
  __shared__ int carry_s;
  const int tid = threadIdx.x;
  const int lane = tid & 63;
  const int wv = tid >> 6;
  if (tid == 0) carry_s = 0;
  __syncthreads();
  for (int base = 0; base < N; base += 1024) {
    int i = base + tid;
    int v = (i < N) ? counts[i] : 0;
    int x = v;
    #pragma unroll
    for (int off = 1; off < 64; off <<= 1) {
      int y = __shfl_up(x, (unsigned)off, 64);
      if (lane >= off) x += y;
    }
    if (lane == 63) wsum[wv] = x;
    __syncthreads();
    if (wv == 0) {
      int s = (lane < 16) ? wsum[lane] : 0;
      #pragma unroll
      for (int off = 1; off < 16; off <<= 1) {
        int y = __shfl_up(s, (unsigned)off, 64);
        if (lane >= off) s += y;
      }
      if (lane < 16) wsum[lane] = s;
    }
    __syncthreads();
    int waveoff = (wv == 0) ? 0 : wsum[wv - 1];
    int excl = carry_s + waveoff + (x - v);
    if (i < N) { row_ptr[i] = excl; cursor[i] = excl; }
    __syncthreads();
    if (tid == 0) carry_s += wsum[15];
    __syncthreads();
  }
  if (tid == 0) row_ptr[N] = carry_s;
}

__global__ __launch_bounds__(DTHREADS) void fill_kernel(
    const int* __restrict__ src, const int* __restrict__ dst,
    int* __restrict__ cursor, int* __restrict__ csr_src, int E) {
  int e = blockIdx.x * DTHREADS + threadIdx.x;
  if (e >= E) return;
  int slot = atomicAdd(&cursor[dst[e]], 1);
  csr_src[slot] = src[e];
}

// ---- weight pack: fp32 [J][K] -> bf16 MFMA B-fragment order --------------
// frag f = ((jb*4 + t)*4 + s)*64 + l holds 8 bf16:
//   j = jb*64 + t*16 + (l&15), k = s*32 + (l>>4)*8 + i
__global__ __launch_bounds__(DTHREADS) void pack_w_kernel(
    const float* __restrict__ w, unsigned short* __restrict__ wpk, int J) {
  int f = blockIdx.x * DTHREADS + threadIdx.x;
  if (f >= J * 16) return;
  int l = f & 63;
  int s = (f >> 6) & 3;
  int t = (f >> 8) & 3;
  int jb = f >> 10;
  int j = jb * 64 + t * 16 + (l & 15);
  int kb = s * 32 + (l >> 4) * 8;
  unsigned short o[8];
  #pragma unroll
  for (int i = 0; i < 8; ++i) o[i] = f2bf_rne(w[j * 128 + kb + i]);
  *(uint4*)&wpk[(size_t)f * 8] = *(uint4*)o;
}

// ---- combined weight: Wc[k][j] = sum_d conv[k][d]*w_ih[j][d], packed -----
__global__ __launch_bounds__(DTHREADS) void pack_wc_kernel(
    const float* __restrict__ conv, const float* __restrict__ w_ih,
    unsigned short* __restrict__ wpk) {
  int f = blockIdx.x * DTHREADS + threadIdx.x;
  if (f >= 384 * 16) return;
  int l = f & 63;
  int s = (f >> 6) & 3;
  int t = (f >> 8) & 3;
  int jb = f >> 10;
  int j = jb * 64 + t * 16 + (l & 15);
  int kb = s * 32 + (l >> 4) * 8;
  unsigned short o[8];
  #pragma unroll
  for (int i = 0; i < 8; ++i) {
    int k = kb + i;
    float acc = 0.f;
    for (int d = 0; d < 128; d += 4) {
      float4 cv = *(const float4*)&conv[k * 128 + d];
      float4 wv = *(const float4*)&w_ih[j * 128 + d];
      acc += cv.x * wv.x + cv.y * wv.y + cv.z * wv.z + cv.w * wv.w;
    }
    o[i] = f2bf_rne(acc);
  }
  *(uint4*)&wpk[(size_t)f * 8] = *(uint4*)o;
}

// ---- bf16 MFMA GEMM: C[N x J](bf16) = A[N x 128](bf16) @ Wpk^T + bias ----
__global__ __launch_bounds__(DTHREADS) void mfma_gemm(
    const unsigned short* __restrict__ A, const unsigned short* __restrict__ Wpk,
    const float* __restrict__ bias, unsigned short* __restrict__ C, int N, int J) {
  __shared__ __align__(16) unsigned short As[128 * 128];  // 32 KB
  const int tid = threadIdx.x;
  const int n0 = blockIdx.x * 128;
  const int jb = blockIdx.y;

  #pragma unroll
  for (int it = 0; it < 8; ++it) {
    int c = it * 256 + tid;
    int row = c >> 4, col = c & 15;
    int n = n0 + row;
    uint4 v = make_uint4(0, 0, 0, 0);
    if (n < N) v = *(const uint4*)&A[(size_t)n * 128 + col * 8];
    int dc = col ^ (row & 15);
    *(uint4*)&As[row * 128 + dc * 8] = v;
  }
  __syncthreads();

  const int wv = tid >> 6, lane = tid & 63;
  const int lm = lane & 15, quad = lane >> 4;

  f32x4 acc[2][4];
  #pragma unroll
  for (int a = 0; a < 2; ++a)
    #pragma unroll
    for (int b = 0; b < 4; ++b) acc[a][b] = (f32x4){0.f, 0.f, 0.f, 0.f};

  const unsigned short* wbase = Wpk + (size_t)jb * 1024 * 8;

  #pragma unroll
  for (int s = 0; s < 4; ++s) {
    bf16x8 afr[2];
    #pragma unroll
    for (int mi = 0; mi < 2; ++mi) {
      int m = wv * 32 + mi * 16 + lm;
      int chunk = (s * 4 + quad) ^ (m & 15);
      afr[mi] = *(const bf16x8*)&As[m * 128 + chunk * 8];
    }
    #pragma unroll
    for (int t = 0; t < 4; ++t) {
      bf16x8 bfr = *(const bf16x8*)&wbase[((size_t)(t * 4 + s) * 64 + lane) * 8];
      acc[0][t] = __builtin_amdgcn_mfma_f32_16x16x32_bf16(afr[0], bfr, acc[0][t], 0, 0, 0);
      acc[1][t] = __builtin_amdgcn_mfma_f32_16x16x32_bf16(afr[1], bfr, acc[1][t], 0, 0, 0);
    }
  }

  // C/D layout: col = lane&15, row = quad*4 + reg
  #pragma unroll
  for (int mi = 0; mi < 2; ++mi) {
    int nbase = n0 + wv * 32 + mi * 16 + quad * 4;
    #pragma unroll
    for (int t = 0; t < 4; ++t) {
      int j = jb * 64 + t * 16 + lm;
      float bv = bias ? bias[j] : 0.f;
      #pragma unroll
      for (int r = 0; r < 4; ++r) {
        int n = nbase + r;
        if (n < N) C[(size_t)n * J + j] = f2bf_rne(acc[mi][t][r] + bv);
      }
    }
  }
}

// ---- CSR aggregate: 4 edges/iter, uint4 row chunks, shfl reduce ----------
// aggH[n,:] = sum_{e: dst==n} hb[src[e],:]  (fp32 accum, bf16 out)
__global__ __launch_bounds__(DTHREADS) void aggregate_kernel(
    const unsigned short* __restrict__ hb, const int* __restrict__ row_ptr,
    const int* __restrict__ csr_src, unsigned short* __restrict__ agg, int N) {
  int w = (blockIdx.x * DTHREADS + threadIdx.x) >> 6;
  if (w >= N) return;
  int lane = threadIdx.x & 63;
  int g = lane >> 4;   // edge subgroup 0..3
  int c = lane & 15;   // 16B chunk (8 bf16)
  int s = row_ptr[w], e = row_ptr[w + 1];
  float acc[8] = {0.f, 0.f, 0.f, 0.f, 0.f, 0.f, 0.f, 0.f};
  #pragma unroll 2
  for (int i = s; i < e; i += 4) {
    int ii = i + g;
    bool valid = ii < e;
    int src = csr_src[valid ? ii : s];
    uint4 v = *(const uint4*)&hb[(size_t)src * 128 + c * 8];
    if (valid) {
      const unsigned int* vp = (const unsigned int*)&v;
      #pragma unroll
      for (int q = 0; q < 4; ++q) {
        acc[2 * q]     += bf2f(vp[q] & 0xffffu);
        acc[2 * q + 1] += bf2f(vp[q] >> 16);
      }
    }
  }
  #pragma unroll
  for (int q = 0; q < 8; ++q) acc[q] += __shfl_xor(acc[q], 16, 64);
  #pragma unroll
  for (int q = 0; q < 8; ++q) acc[q] += __shfl_xor(acc[q], 32, 64);
  if (g == 0) {
    unsigned int o[4];
    #pragma unroll
    for (int q = 0; q < 4; ++q)
      o[q] = (unsigned int)f2bf_rne(acc[2 * q]) | ((unsigned int)f2bf_rne(acc[2 * q + 1]) << 16);
    *(uint4*)&agg[(size_t)w * 128 + c * 8] = *(uint4*)o;
  }
}

// ---- GRU gates, bf16 in/out, in-place h-state update ---------------------
__global__ __launch_bounds__(DTHREADS) void gates_kernel(
    const unsigned short* __restrict__ gi, const unsigned short* __restrict__ gh,
    unsigned short* __restrict__ hb, int N) {
  int idx = blockIdx.x * DTHREADS + threadIdx.x;
  if (idx >= N * 16) return;
  int n = idx >> 4;
  int j8 = (idx & 15) * 8;
  size_t gbase = (size_t)n * 384 + j8;
  uint4 ir4 = *(const uint4*)&gi[gbase];
  uint4 iz4 = *(const uint4*)&gi[gbase + 128];
  uint4 in4 = *(const uint4*)&gi[gbase + 256];
  uint4 hr4 = *(const uint4*)&gh[gbase];
  uint4 hz4 = *(const uint4*)&gh[gbase + 128];
  uint4 hn4 = *(const uint4*)&gh[gbase + 256];
  uint4 hv4 = *(const uint4*)&hb[(size_t)n * 128 + j8];
  const unsigned int* irp = (const unsigned int*)&ir4;
  const unsigned int* izp = (const unsigned int*)&iz4;
  const unsigned int* inp = (const unsigned int*)&in4;
  const unsigned int* hrp = (const unsigned int*)&hr4;
  const unsigned int* hzp = (const unsigned int*)&hz4;
  const unsigned int* hnp = (const unsigned int*)&hn4;
  const unsigned int* hvp = (const unsigned int*)&hv4;
  unsigned int o[4];
  #pragma unroll
  for (int q = 0; q < 4; ++q) {
    float olo, ohi;
    {
      float r = sigf(bf2f(irp[q] & 0xffffu) + bf2f(hrp[q] & 0xffffu));
      float z = sigf(bf2f(izp[q] & 0xffffu) + bf2f(hzp[q] & 0xffffu));
      float ng = tanhfast(bf2f(inp[q] & 0xffffu) + r * bf2f(hnp[q] & 0xffffu));
      olo = (1.f - z) * ng + z * bf2f(hvp[q] & 0xffffu);
    }
    {
      float r = sigf(bf2f(irp[q] >> 16) + bf2f(hrp[q] >> 16));
      float z = sigf(bf2f(izp[q] >> 16) + bf2f(hzp[q] >> 16));
      float ng = tanhfast(bf2f(inp[q] >> 16) + r * bf2f(hnp[q] >> 16));
      ohi = (1.f - z) * ng + z * bf2f(hvp[q] >> 16);
    }
    o[q] = (unsigned int)f2bf_rne(olo) | ((unsigned int)f2bf_rne(ohi) << 16);
  }
  *(uint4*)&hb[(size_t)n * 128 + j8] = *(uint4*)o;
}

// ---- two-stage mean pool over bf16 h-state -------------------------------
__global__ __launch_bounds__(DTHREADS) void pool1_kernel(
    const unsigned short* __restrict__ hb, const int* __restrict__ batch,
    float* __restrict__ outsum, int N) {
  int b = blockIdx.x;
  int c = threadIdx.x & 127;
  int half = threadIdx.x >> 7;
  int nbeg = b * 64;
  int nend = min(nbeg + 64, N);
  float acc = 0.f;
  int cur = -1;
  for (int n = nbeg + half; n < nend; n += 2) {
    int g = batch[n];
    if (g != cur) {
      if (cur >= 0) atomicAdd(&outsum[(size_t)cur * 128 + c], acc);
      acc = 0.f;
      cur = g;
    }
    acc += bf2f((unsigned int)hb[(size_t)n * 128 + c]);
  }
  if (cur >= 0) atomicAdd(&outsum[(size_t)cur * 128 + c], acc);
}

__device__ __forceinline__ int lbound(const int* a, int n, int key) {
  int lo = 0, hi = n;
  while (lo < hi) {
    int mid = (lo + hi) >> 1;
    if (a[mid] < key) lo = mid + 1; else hi = mid;
  }
  return lo;
}

__global__ __launch_bounds__(128) void pool2_kernel(
    const float* __restrict__ outsum, const int* __restrict__ batch,
    float* __restrict__ out, int N) {
  int g = blockIdx.x;
  int c = threadIdx.x;
  int lo = lbound(batch, N, g);
  int hi = lbound(batch, N, g + 1);
  out[(size_t)g * 128 + c] = outsum[(size_t)g * 128 + c] / (float)max(hi - lo, 1);
}

extern "C" void kernel_launch(void* const* d_in, const int* in_sizes, int n_in,
                              void* d_out, int out_size, void* d_ws, size_t ws_size,
                              hipStream_t stream) {
  const int* node_ids = (const int*)d_in[0];
  const int* edge_index = (const int*)d_in[1];
  const int* batch = (const int*)d_in[2];
  const float* embed = (const float*)d_in[4];
  const float* conv_w = (const float*)d_in[5];
  const float* w_ih = (const float*)d_in[6];
  const float* w_hh = (const float*)d_in[7];
  const float* b_ih = (const float*)d_in[8];
  const float* b_hh = (const float*)d_in[9];
  float* out = (float*)d_out;

  const int N = in_sizes[0];
  const int E = in_sizes[1] / 2;
  const int G = out_size / 128;
  const int NUM_LAYERS = in_sizes[5] / (128 * 128);

  const int* e_src = edge_index;
  const int* e_dst = edge_index + E;

  // ---- workspace carve-up (16B aligned) ----
  char* p = (char*)d_ws;
  unsigned short* hb = (unsigned short*)p;    p += (size_t)N * 128 * 2;
  unsigned short* aggb = (unsigned short*)p;  p += (size_t)N * 128 * 2;
  unsigned short* gi = (unsigned short*)p;    p += (size_t)N * 384 * 2;
  unsigned short* gh = (unsigned short*)p;    p += (size_t)N * 384 * 2;
  float* outsum = (float*)p;                  p += (size_t)G * 128 * 4;
  unsigned short* wpk_hh = (unsigned short*)p; p += (size_t)384 * 128 * 2;
  unsigned short* wpk_wc = (unsigned short*)p; p += (size_t)NUM_LAYERS * 384 * 128 * 2;
  int* row_ptr = (int*)p;  p += (size_t)(N + 1) * 4;
  int* counts = (int*)p;   p += (size_t)N * 4;
  int* cursor = (int*)p;   p += (size_t)N * 4;
  int* csr_src = (int*)p;  p += (size_t)E * 4;

  // CSR build (reused by both layers)
  hipMemsetAsync(counts, 0, (size_t)N * sizeof(int), stream);
  hipMemsetAsync(outsum, 0, (size_t)G * 128 * sizeof(float), stream);
  hist_kernel<<<(E + DTHREADS - 1) / DTHREADS, DTHREADS, 0, stream>>>(e_dst, counts, E);
  scan_kernel<<<1, 1024, 0, stream>>>(counts, row_ptr, cursor, N);
  fill_kernel<<<(E + DTHREADS - 1) / DTHREADS, DTHREADS, 0, stream>>>(e_src, e_dst, cursor, csr_src, E);

  // weight prep: w_hh fragment-packed; Wc[L] = conv_w[L] @ w_ih^T packed
  pack_w_kernel<<<(384 * 16 + DTHREADS - 1) / DTHREADS, DTHREADS, 0, stream>>>(w_hh, wpk_hh, 384);
  for (int L = 0; L < NUM_LAYERS; ++L)
    pack_wc_kernel<<<(384 * 16 + DTHREADS - 1) / DTHREADS, DTHREADS, 0, stream>>>(
        conv_w + (size_t)L * 128 * 128, w_ih, wpk_wc + (size_t)L * 384 * 128);

  gather_kernel<<<(N * 32 + DTHREADS - 1) / DTHREADS, DTHREADS, 0, stream>>>(embed, node_ids, hb, N);

  const int nb = (N + 127) / 128;
  for (int L = 0; L < NUM_LAYERS; ++L) {
    // aggH = segsum(hb[src]) ; gi = aggH @ Wc[L] + b_ih ; gh = hb @ w_hh^T + b_hh
    aggregate_kernel<<<((size_t)N * 64 + DTHREADS - 1) / DTHREADS, DTHREADS, 0, stream>>>(
        hb, row_ptr, csr_src, aggb, N);
    mfma_gemm<<<dim3(nb, 6), DTHREADS, 0, stream>>>(
        aggb, wpk_wc + (size_t)L * 384 * 128, b_ih, gi, N, 384);
    mfma_gemm<<<dim3(nb, 6), DTHREADS, 0, stream>>>(hb, wpk_hh, b_hh, gh, N, 384);
    gates_kernel<<<(N * 16 + DTHREADS - 1) / DTHREADS, DTHREADS, 0, stream>>>(gi, gh, hb, N);
  }

  pool1_kernel<<<(N + 63) / 64, DTHREADS, 0, stream>>>(hb, batch, outsum, N);
  pool2_kernel<<<G, 128, 0, stream>>>(outsum, batch, out, N);
}

// Round 4
// 388.504 us; speedup vs baseline: 2.3953x; 1.4846x over previous
//
#include <hip/hip_runtime.h>
#include <hip/hip_bf16.h>

// GatedConv: N=50000, E=800000, D=128, G=64, 2 layers.
// Round 3: (a) parallel reduce-then-scan CSR row_ptr build (was 51us single
// block); (b) gi-GEMM + gh-GEMM + GRU gates fused into one MFMA kernel
// (gi/gh never touch HBM); (c) pack_wc parallelized 8x.

#define DTHREADS 256

typedef __attribute__((ext_vector_type(8))) short bf16x8;
typedef __attribute__((ext_vector_type(4))) float f32x4;

__device__ __forceinline__ float sigf(float x) { return 1.0f / (1.0f + __expf(-x)); }
__device__ __forceinline__ float tanhfast(float x) { return 1.0f - 2.0f / (1.0f + __expf(2.0f * x)); }

__device__ __forceinline__ unsigned short f2bf_rne(float x) {
  unsigned int u = __float_as_uint(x);
  u += 0x7fff + ((u >> 16) & 1);
  return (unsigned short)(u >> 16);
}
__device__ __forceinline__ float bf2f(unsigned int lo16) {
  return __uint_as_float(lo16 << 16);
}

// ---- embed gather: hb[n,:] = bf16(embed[node_ids[n],:]) ------------------
__global__ __launch_bounds__(DTHREADS) void gather_kernel(
    const float* __restrict__ embed, const int* __restrict__ node_ids,
    unsigned short* __restrict__ hb, int N) {
  int idx = blockIdx.x * DTHREADS + threadIdx.x;
  if (idx >= N * 32) return;
  int n = idx >> 5;
  int c = (idx & 31) * 4;
  int v = node_ids[n];
  float4 val = *(const float4*)&embed[(size_t)v * 128 + c];
  unsigned short b[4] = {f2bf_rne(val.x), f2bf_rne(val.y), f2bf_rne(val.z), f2bf_rne(val.w)};
  *(ushort4*)&hb[(size_t)n * 128 + c] = *(ushort4*)b;
}

// ---- CSR build ------------------------------------------------------------
__global__ __launch_bounds__(DTHREADS) void hist_kernel(
    const int* __restrict__ dst, int* __restrict__ counts, int E) {
  int e = blockIdx.x * DTHREADS + threadIdx.x;
  if (e < E) atomicAdd(&counts[dst[e]], 1);
}

// scan stage 1: per-1024-chunk sums
__global__ __launch_bounds__(DTHREADS) void scan_sum_kernel(
    const int* __restrict__ counts, int* __restrict__ bsum, int N) {
  int b = blockIdx.x;
  int tid = threadIdx.x;
  int lane = tid & 63, wv = tid >> 6;
  int s = 0;
  #pragma unroll
  for (int it = 0; it < 4; ++it) {
    int i = b * 1024 + it * 256 + tid;
    if (i < N) s += counts[i];
  }
  #pragma unroll
  for (int off = 32; off >= 1; off >>= 1) s += __shfl_xor(s, off, 64);
  __shared__ int ws[4];
  if (lane == 0) ws[wv] = s;
  __syncthreads();
  if (tid == 0) bsum[b] = ws[0] + ws[1] + ws[2] + ws[3];
}

// scan stage 2: exclusive scan of nb (<=256) block sums in place; total -> row_ptr[N]
__global__ __launch_bounds__(DTHREADS) void scan_top_kernel(
    int* __restrict__ bsum, int* __restrict__ row_ptr, int nb, int N) {
  int tid = threadIdx.x;
  int lane = tid & 63, wv = tid >> 6;
  int v = (tid < nb) ? bsum[tid] : 0;
  int x = v;
  #pragma unroll
  for (int off = 1; off < 64; off <<= 1) {
    int y = __shfl_up(x, (unsigned)off, 64);
    if (lane >= off) x += y;
  }
  __shared__ int ws[4];
  if (lane == 63) ws[wv] = x;
  __syncthreads();
  int woff = 0;
  for (int w = 0; w < wv; ++w) woff += ws[w];
  x += woff;
  if (tid < nb) bsum[tid] = x - v;
  if (tid == nb - 1) row_ptr[N] = x;
}

// scan stage 3: recompute local prefix, add block base, write row_ptr & cursor
__global__ __launch_bounds__(DTHREADS) void scan_apply_kernel(
    const int* __restrict__ counts, const int* __restrict__ bsum,
    int* __restrict__ row_ptr, int* __restrict__ cursor, int N) {
  int b = blockIdx.x;
  int tid = threadIdx.x;
  int lane = tid & 63, wv = tid >> 6;
  int base = b * 1024 + tid * 4;
  int v[4];
  #pragma unroll
  for (int q = 0; q < 4; ++q) v[q] = (base + q < N) ? counts[base + q] : 0;
  int ts = v[0] + v[1] + v[2] + v[3];
  int xs = ts;
  #pragma unroll
  for (int off = 1; off < 64; off <<= 1) {
    int y = __shfl_up(xs, (unsigned)off, 64);
    if (lane >= off) xs += y;
  }
  __shared__ int ws[4];
  if (lane == 63) ws[wv] = xs;
  __syncthreads();
  int off = bsum[b];
  for (int w = 0; w < wv; ++w) off += ws[w];
  int e = off + (xs - ts);
  #pragma unroll
  for (int q = 0; q < 4; ++q) {
    int i = base + q;
    if (i < N) { row_ptr[i] = e; cursor[i] = e; }
    e += v[q];
  }
}

__global__ __launch_bounds__(DTHREADS) void fill_kernel(
    const int* __restrict__ src, const int* __restrict__ dst,
    int* __restrict__ cursor, int* __restrict__ csr_src, int E) {
  int e = blockIdx.x * DTHREADS + threadIdx.x;
  if (e >= E) return;
  int slot = atomicAdd(&cursor[dst[e]], 1);
  csr_src[slot] = src[e];
}

// ---- weight pack: fp32 [J][K] -> bf16 MFMA B-fragment order --------------
// frag f = ((jb*4 + t)*4 + s)*64 + l holds 8 bf16:
//   j = jb*64 + t*16 + (l&15), k = s*32 + (l>>4)*8 + i
__global__ __launch_bounds__(DTHREADS) void pack_w_kernel(
    const float* __restrict__ w, unsigned short* __restrict__ wpk, int J) {
  int f = blockIdx.x * DTHREADS + threadIdx.x;
  if (f >= J * 16) return;
  int l = f & 63;
  int s = (f >> 6) & 3;
  int t = (f >> 8) & 3;
  int jb = f >> 10;
  int j = jb * 64 + t * 16 + (l & 15);
  int kb = s * 32 + (l >> 4) * 8;
  unsigned short o[8];
  #pragma unroll
  for (int i = 0; i < 8; ++i) o[i] = f2bf_rne(w[j * 128 + kb + i]);
  *(uint4*)&wpk[(size_t)f * 8] = *(uint4*)o;
}

// ---- combined weight Wc[k][j] = conv[k][:] . w_ih[j][:], one thread/elem -
__global__ __launch_bounds__(DTHREADS) void pack_wc_kernel(
    const float* __restrict__ conv, const float* __restrict__ w_ih,
    unsigned short* __restrict__ wpk) {
  int id = blockIdx.x * DTHREADS + threadIdx.x;
  if (id >= 384 * 128) return;
  int f = id >> 3, i = id & 7;
  int l = f & 63;
  int s = (f >> 6) & 3;
  int t = (f >> 8) & 3;
  int jb = f >> 10;
  int j = jb * 64 + t * 16 + (l & 15);
  int k = s * 32 + (l >> 4) * 8 + i;
  float acc = 0.f;
  for (int d = 0; d < 128; d += 4) {
    float4 cv = *(const float4*)&conv[k * 128 + d];
    float4 wv = *(const float4*)&w_ih[j * 128 + d];
    acc += cv.x * wv.x + cv.y * wv.y + cv.z * wv.z + cv.w * wv.w;
  }
  wpk[(size_t)f * 8 + i] = f2bf_rne(acc);
}

// ---- CSR aggregate: 4 edges/iter, uint4 row chunks, shfl reduce ----------
__global__ __launch_bounds__(DTHREADS) void aggregate_kernel(
    const unsigned short* __restrict__ hb, const int* __restrict__ row_ptr,
    const int* __restrict__ csr_src, unsigned short* __restrict__ agg, int N) {
  int w = (blockIdx.x * DTHREADS + threadIdx.x) >> 6;
  if (w >= N) return;
  int lane = threadIdx.x & 63;
  int g = lane >> 4;   // edge subgroup 0..3
  int c = lane & 15;   // 16B chunk (8 bf16)
  int s = row_ptr[w], e = row_ptr[w + 1];
  float acc[8] = {0.f, 0.f, 0.f, 0.f, 0.f, 0.f, 0.f, 0.f};
  #pragma unroll 2
  for (int i = s; i < e; i += 4) {
    int ii = i + g;
    bool valid = ii < e;
    int src = csr_src[valid ? ii : s];
    uint4 v = *(const uint4*)&hb[(size_t)src * 128 + c * 8];
    if (valid) {
      const unsigned int* vp = (const unsigned int*)&v;
      #pragma unroll
      for (int q = 0; q < 4; ++q) {
        acc[2 * q]     += bf2f(vp[q] & 0xffffu);
        acc[2 * q + 1] += bf2f(vp[q] >> 16);
      }
    }
  }
  #pragma unroll
  for (int q = 0; q < 8; ++q) acc[q] += __shfl_xor(acc[q], 16, 64);
  #pragma unroll
  for (int q = 0; q < 8; ++q) acc[q] += __shfl_xor(acc[q], 32, 64);
  if (g == 0) {
    unsigned int o[4];
    #pragma unroll
    for (int q = 0; q < 4; ++q)
      o[q] = (unsigned int)f2bf_rne(acc[2 * q]) | ((unsigned int)f2bf_rne(acc[2 * q + 1]) << 16);
    *(uint4*)&agg[(size_t)w * 128 + c * 8] = *(uint4*)o;
  }
}

// ---- fused: gi = agg@Wc + b_ih ; gh = hb@Whh + b_hh ; hb = GRU(gi,gh,hb) -
// Block = 32 rows. Wave wv owns hidden cols [wv*32, wv*32+32). Per wave:
// 2 rowtiles x 2 coltiles x 3 gates x 2 matrices = 24 MFMA acc tiles (96 VGPR).
__global__ __launch_bounds__(DTHREADS) void fused_gru_kernel(
    const unsigned short* __restrict__ aggb, const unsigned short* __restrict__ wpk_wc,
    const unsigned short* __restrict__ wpk_hh, const float* __restrict__ b_ih,
    const float* __restrict__ b_hh, unsigned short* __restrict__ hb, int N) {
  __shared__ __align__(16) unsigned short Ag[32 * 128];  // 8 KB, xor-swizzled
  __shared__ __align__(16) unsigned short Hs[32 * 128];  // 8 KB
  const int tid = threadIdx.x;
  const int n0 = blockIdx.x * 32;

  #pragma unroll
  for (int it = 0; it < 2; ++it) {
    int c = it * 256 + tid;      // 0..511
    int row = c >> 4, col = c & 15;
    int n = n0 + row;
    uint4 va = make_uint4(0, 0, 0, 0), vh = make_uint4(0, 0, 0, 0);
    if (n < N) {
      va = *(const uint4*)&aggb[(size_t)n * 128 + col * 8];
      vh = *(const uint4*)&hb[(size_t)n * 128 + col * 8];
    }
    int dc = col ^ (row & 15);
    *(uint4*)&Ag[row * 128 + dc * 8] = va;
    *(uint4*)&Hs[row * 128 + dc * 8] = vh;
  }
  __syncthreads();

  const int wv = tid >> 6, lane = tid & 63;
  const int lm = lane & 15, quad = lane >> 4;

  f32x4 accI[2][2][3], accH[2][2][3];  // [mi(rowtile)][u(coltile)][gate]
  #pragma unroll
  for (int mi = 0; mi < 2; ++mi)
    #pragma unroll
    for (int u = 0; u < 2; ++u)
      #pragma unroll
      for (int g = 0; g < 3; ++g) {
        accI[mi][u][g] = (f32x4){0.f, 0.f, 0.f, 0.f};
        accH[mi][u][g] = (f32x4){0.f, 0.f, 0.f, 0.f};
      }

  #pragma unroll
  for (int s = 0; s < 4; ++s) {
    bf16x8 afA[2], afH[2];
    #pragma unroll
    for (int mi = 0; mi < 2; ++mi) {
      int m = mi * 16 + lm;
      int chunk = (s * 4 + quad) ^ (m & 15);
      afA[mi] = *(const bf16x8*)&Ag[m * 128 + chunk * 8];
      afH[mi] = *(const bf16x8*)&Hs[m * 128 + chunk * 8];
    }
    #pragma unroll
    for (int g = 0; g < 3; ++g) {
      int jb = g * 2 + (wv >> 1);
      #pragma unroll
      for (int u = 0; u < 2; ++u) {
        int t = (wv & 1) * 2 + u;
        size_t f = ((size_t)(jb * 4 + t) * 4 + s) * 64 + lane;
        bf16x8 bI = *(const bf16x8*)&wpk_wc[f * 8];
        bf16x8 bH = *(const bf16x8*)&wpk_hh[f * 8];
        #pragma unroll
        for (int mi = 0; mi < 2; ++mi) {
          accI[mi][u][g] = __builtin_amdgcn_mfma_f32_16x16x32_bf16(afA[mi], bI, accI[mi][u][g], 0, 0, 0);
          accH[mi][u][g] = __builtin_amdgcn_mfma_f32_16x16x32_bf16(afH[mi], bH, accH[mi][u][g], 0, 0, 0);
        }
      }
    }
  }

  // Epilogue: gate math in-register. C/D layout: col = lane&15, row = quad*4+reg.
  #pragma unroll
  for (int u = 0; u < 2; ++u) {
    int jc = wv * 32 + u * 16 + lm;         // hidden col 0..127
    float bir = b_ih[jc], biz = b_ih[128 + jc], bin_ = b_ih[256 + jc];
    float bhr = b_hh[jc], bhz = b_hh[128 + jc], bhn = b_hh[256 + jc];
    int c0 = jc >> 3, ej = jc & 7;
    #pragma unroll
    for (int mi = 0; mi < 2; ++mi) {
      #pragma unroll
      for (int r = 0; r < 4; ++r) {
        int row = mi * 16 + quad * 4 + r;
        int n = n0 + row;
        if (n >= N) continue;
        float ir = accI[mi][u][0][r] + bir;
        float iz = accI[mi][u][1][r] + biz;
        float in_ = accI[mi][u][2][r] + bin_;
        float hr = accH[mi][u][0][r] + bhr;
        float hz = accH[mi][u][1][r] + bhz;
        float hn = accH[mi][u][2][r] + bhn;
        float rr = sigf(ir + hr);
        float zz = sigf(iz + hz);
        float nn = tanhfast(in_ + rr * hn);
        float hold = bf2f((unsigned int)Hs[row * 128 + ((c0 ^ (row & 15)) * 8) + ej]);
        hb[(size_t)n * 128 + jc] = f2bf_rne((1.f - zz) * nn + zz * hold);
      }
    }
  }
}

// ---- two-stage mean pool over bf16 h-state -------------------------------
__global__ __launch_bounds__(DTHREADS) void pool1_kernel(
    const unsigned short* __restrict__ hb, const int* __restrict__ batch,
    float* __restrict__ outsum, int N) {
  int b = blockIdx.x;
  int c = threadIdx.x & 127;
  int half = threadIdx.x >> 7;
  int nbeg = b * 64;
  int nend = min(nbeg + 64, N);
  float acc = 0.f;
  int cur = -1;
  for (int n = nbeg + half; n < nend; n += 2) {
    int g = batch[n];
    if (g != cur) {
      if (cur >= 0) atomicAdd(&outsum[(size_t)cur * 128 + c], acc);
      acc = 0.f;
      cur = g;
    }
    acc += bf2f((unsigned int)hb[(size_t)n * 128 + c]);
  }
  if (cur >= 0) atomicAdd(&outsum[(size_t)cur * 128 + c], acc);
}

__device__ __forceinline__ int lbound(const int* a, int n, int key) {
  int lo = 0, hi = n;
  while (lo < hi) {
    int mid = (lo + hi) >> 1;
    if (a[mid] < key) lo = mid + 1; else hi = mid;
  }
  return lo;
}

__global__ __launch_bounds__(128) void pool2_kernel(
    const float* __restrict__ outsum, const int* __restrict__ batch,
    float* __restrict__ out, int N) {
  int g = blockIdx.x;
  int c = threadIdx.x;
  int lo = lbound(batch, N, g);
  int hi = lbound(batch, N, g + 1);
  out[(size_t)g * 128 + c] = outsum[(size_t)g * 128 + c] / (float)max(hi - lo, 1);
}

extern "C" void kernel_launch(void* const* d_in, const int* in_sizes, int n_in,
                              void* d_out, int out_size, void* d_ws, size_t ws_size,
                              hipStream_t stream) {
  const int* node_ids = (const int*)d_in[0];
  const int* edge_index = (const int*)d_in[1];
  const int* batch = (const int*)d_in[2];
  const float* embed = (const float*)d_in[4];
  const float* conv_w = (const float*)d_in[5];
  const float* w_ih = (const float*)d_in[6];
  const float* w_hh = (const float*)d_in[7];
  const float* b_ih = (const float*)d_in[8];
  const float* b_hh = (const float*)d_in[9];
  float* out = (float*)d_out;

  const int N = in_sizes[0];
  const int E = in_sizes[1] / 2;
  const int G = out_size / 128;
  const int NUM_LAYERS = in_sizes[5] / (128 * 128);

  const int* e_src = edge_index;
  const int* e_dst = edge_index + E;

  // ---- workspace carve-up (16B aligned) ----
  char* p = (char*)d_ws;
  unsigned short* hb = (unsigned short*)p;    p += (size_t)N * 128 * 2;
  unsigned short* aggb = (unsigned short*)p;  p += (size_t)N * 128 * 2;
  float* outsum = (float*)p;                  p += (size_t)G * 128 * 4;
  unsigned short* wpk_hh = (unsigned short*)p; p += (size_t)384 * 128 * 2;
  unsigned short* wpk_wc = (unsigned short*)p; p += (size_t)NUM_LAYERS * 384 * 128 * 2;
  int* row_ptr = (int*)p;  p += (size_t)(N + 1) * 4;
  int* counts = (int*)p;   p += (size_t)N * 4;
  int* cursor = (int*)p;   p += (size_t)N * 4;
  int* bsum = (int*)p;     p += 256 * 4;
  int* csr_src = (int*)p;  p += (size_t)E * 4;

  const int nchunks = (N + 1023) / 1024;  // 49 for N=50000 (<=256 required)

  // CSR build (reused by both layers)
  hipMemsetAsync(counts, 0, (size_t)N * sizeof(int), stream);
  hipMemsetAsync(outsum, 0, (size_t)G * 128 * sizeof(float), stream);
  hist_kernel<<<(E + DTHREADS - 1) / DTHREADS, DTHREADS, 0, stream>>>(e_dst, counts, E);
  scan_sum_kernel<<<nchunks, DTHREADS, 0, stream>>>(counts, bsum, N);
  scan_top_kernel<<<1, DTHREADS, 0, stream>>>(bsum, row_ptr, nchunks, N);
  scan_apply_kernel<<<nchunks, DTHREADS, 0, stream>>>(counts, bsum, row_ptr, cursor, N);
  fill_kernel<<<(E + DTHREADS - 1) / DTHREADS, DTHREADS, 0, stream>>>(e_src, e_dst, cursor, csr_src, E);

  // weight prep: w_hh fragment-packed; Wc[L] = conv_w[L] @ w_ih^T packed
  pack_w_kernel<<<(384 * 16 + DTHREADS - 1) / DTHREADS, DTHREADS, 0, stream>>>(w_hh, wpk_hh, 384);
  for (int L = 0; L < NUM_LAYERS; ++L)
    pack_wc_kernel<<<(384 * 128 + DTHREADS - 1) / DTHREADS, DTHREADS, 0, stream>>>(
        conv_w + (size_t)L * 128 * 128, w_ih, wpk_wc + (size_t)L * 384 * 128);

  gather_kernel<<<(N * 32 + DTHREADS - 1) / DTHREADS, DTHREADS, 0, stream>>>(embed, node_ids, hb, N);

  const int nb32 = (N + 31) / 32;
  for (int L = 0; L < NUM_LAYERS; ++L) {
    aggregate_kernel<<<((size_t)N * 64 + DTHREADS - 1) / DTHREADS, DTHREADS, 0, stream>>>(
        hb, row_ptr, csr_src, aggb, N);
    fused_gru_kernel<<<nb32, DTHREADS, 0, stream>>>(
        aggb, wpk_wc + (size_t)L * 384 * 128, wpk_hh, b_ih, b_hh, hb, N);
  }

  pool1_kernel<<<(N + 63) / 64, DTHREADS, 0, stream>>>(hb, batch, outsum, N);
  pool2_kernel<<<G, 128, 0, stream>>>(outsum, batch, out, N);
}